// Round 4
// baseline (608.462 us; speedup 1.0000x reference)
//
#include <hip/hip_runtime.h>
#include <hip/hip_bf16.h>

#define IN_F 4096
#define OUT_F 4096
#define M_TOK 8192
#define RANK 16

typedef __attribute__((ext_vector_type(4))) float f32x4;
typedef __attribute__((ext_vector_type(8))) short short8;

struct alignas(16) bf16x8_s { __hip_bfloat16 v[8]; };

// ---------------------------------------------------------------------------
// Kernel 1a: streaming convert x fp32 -> bf16. UNCHANGED (R3 showed the
// occupancy-split theory false; held constant so the GEMM drop lets the slow
// prep kernel enter rocprof's top-5 next round for real attribution).
// ---------------------------------------------------------------------------
#define CONV_BLOCKS 2048
#define CONV_ITERS (M_TOK * IN_F / (8 * 256 * CONV_BLOCKS))   // 8

__global__ __launch_bounds__(256) void conv_kernel(
    const float* __restrict__ x,
    __hip_bfloat16* __restrict__ xb) {
    size_t idx = (size_t)blockIdx.x * 256 + threadIdx.x;
    const size_t stride = (size_t)CONV_BLOCKS * 256;
#pragma unroll
    for (int it = 0; it < CONV_ITERS; ++it, idx += stride) {
        const size_t base = idx * 8;
        float4 v0 = *(const float4*)(x + base);
        float4 v1 = *(const float4*)(x + base + 4);
        bf16x8_s r;
        r.v[0] = __float2bfloat16(v0.x);
        r.v[1] = __float2bfloat16(v0.y);
        r.v[2] = __float2bfloat16(v0.z);
        r.v[3] = __float2bfloat16(v0.w);
        r.v[4] = __float2bfloat16(v1.x);
        r.v[5] = __float2bfloat16(v1.y);
        r.v[6] = __float2bfloat16(v1.z);
        r.v[7] = __float2bfloat16(v1.w);
        *(bf16x8_s*)(xb + base) = r;
    }
}

// ---------------------------------------------------------------------------
// Kernel 1b: dequant int4 codes -> bf16 with rank-16 LoRA folded in. UNCHANGED.
//   W[o][i] = bf16( scales[o][i/64]*(q-8) + 2*sum_r A[i][r]*B[r][o] )
// ---------------------------------------------------------------------------
#define DEQ_BLOCKS 2048

__global__ __launch_bounds__(256) void deq_kernel(
    const int* __restrict__ q,
    const float* __restrict__ scales,
    const float* __restrict__ lA,   // [IN_F][RANK]
    const float* __restrict__ lB,   // [RANK][OUT_F]
    __hip_bfloat16* __restrict__ W) {
    const int tid = threadIdx.x;
    const int bid = blockIdx.x;                  // 0..2047
    const int o0 = (bid >> 1) * 4;               // block-uniform
    const int i0 = (bid & 1) * 2048 + tid * 8;

    float bw[16][4];
#pragma unroll
    for (int r = 0; r < 16; ++r)
#pragma unroll
        for (int oi = 0; oi < 4; ++oi)
            bw[r][oi] = 2.0f * lB[(size_t)r * OUT_F + o0 + oi];

    float fold[4][8];
#pragma unroll
    for (int e = 0; e < 8; ++e) {
        const float* ar = lA + (size_t)(i0 + e) * RANK;
        float4 a0 = *(const float4*)(ar + 0);
        float4 a1 = *(const float4*)(ar + 4);
        float4 a2 = *(const float4*)(ar + 8);
        float4 a3 = *(const float4*)(ar + 12);
#pragma unroll
        for (int oi = 0; oi < 4; ++oi) {
            float f = a0.x * bw[0][oi] + a0.y * bw[1][oi]
                    + a0.z * bw[2][oi] + a0.w * bw[3][oi]
                    + a1.x * bw[4][oi] + a1.y * bw[5][oi]
                    + a1.z * bw[6][oi] + a1.w * bw[7][oi]
                    + a2.x * bw[8][oi] + a2.y * bw[9][oi]
                    + a2.z * bw[10][oi] + a2.w * bw[11][oi]
                    + a3.x * bw[12][oi] + a3.y * bw[13][oi]
                    + a3.z * bw[14][oi] + a3.w * bw[15][oi];
            fold[oi][e] = f;
        }
    }

#pragma unroll
    for (int oi = 0; oi < 4; ++oi) {
        const int o = o0 + oi;
        const float s = scales[o * 64 + (i0 >> 6)];
        const int4* qp = (const int4*)(q + (size_t)o * IN_F + i0);
        int4 q0 = qp[0];
        int4 q1 = qp[1];
        bf16x8_s r;
        r.v[0] = __float2bfloat16(s * (float)(q0.x - 8) + fold[oi][0]);
        r.v[1] = __float2bfloat16(s * (float)(q0.y - 8) + fold[oi][1]);
        r.v[2] = __float2bfloat16(s * (float)(q0.z - 8) + fold[oi][2]);
        r.v[3] = __float2bfloat16(s * (float)(q0.w - 8) + fold[oi][3]);
        r.v[4] = __float2bfloat16(s * (float)(q1.x - 8) + fold[oi][4]);
        r.v[5] = __float2bfloat16(s * (float)(q1.y - 8) + fold[oi][5]);
        r.v[6] = __float2bfloat16(s * (float)(q1.z - 8) + fold[oi][6]);
        r.v[7] = __float2bfloat16(s * (float)(q1.w - 8) + fold[oi][7]);
        *(bf16x8_s*)(W + (size_t)o * IN_F + i0) = r;
    }
}

// ---------------------------------------------------------------------------
// Kernel 2: 256x256 8-phase GEMM. R4 change: SOFTWARE-PIPELINED ds_reads with
// COUNTED lgkmcnt (T4 applied to the LDS side). R3's {reads; barrier;
// lgkmcnt(0); MFMA} serialized the LDS window (2304 cyc/K-tile) against the
// MFMA window (2484 cyc) -> 5570 cyc observed. Now phase p issues the reads
// for phase p+1, then waits lgkmcnt(K=just-issued) so phase p's operands are
// drained while p+1's reads crunch through the LDS pipe DURING the MFMA.
//
// Per-tile phase plan (X = tile's buf, Y = other buf; fa double-buffered,
// fb0 holds B@k0 / fb1 holds B@k1 across the tile):
//   p0: rd fa1<-X.A h0 k1, fb1<-X.B k1 (8); stage Y.A1(t+1);  lgkm(8); MFMA(fa0,fb0,acc0-3)
//   p1: rd fa0<-X.A h1 k0 (4);                               lgkm(4); MFMA(fa1,fb1,acc0-3)
//   p2: rd fa1<-X.A h1 k1 (4); stage X.A0+X.B0(t+2);         lgkm(4); MFMA(fa0,fb0,acc4-7)
//   p3: VMCNT(4); rd fa0<-Y.A h0 k0, fb0<-Y.B k0 (8); stage X.B1(t+2);
//                                                            lgkm(8); MFMA(fa1,fb1,acc4-7)
// vmcnt(4) at p3 TOP (before the next-tile read-issues!): in-flight then =
// [p2(t-1):4][p3(t-1):2][p0(t):2][p2(t):4]=12 -> keeps newest 4 (p2(t)),
// drains ALL of tile t+1's staged data before its first read ISSUES.
// Stage-vs-pending-read audit: each staged region's last read completes at a
// lgkm wait >=1 phase before the stage issues (A1@p0: reads done p3(t-1);
// A0/B0@p2: done p1(t); B1@p3: done p1(t)); pending reads crossing a stage's
// phase never alias its region. Never vmcnt(0)/lgkmcnt(0) in the loop.
// ---------------------------------------------------------------------------
#define BK 64
#define NT (IN_F / BK)   // 64 K-tiles

__device__ __forceinline__ short8 ldfrag(const short* p, int half, int row, int gran) {
    // swizzled read: LDS granule slot (gran ^ (row&7)) holds global granule gran
    return *(const short8*)(p + half * 8192 + row * 64 + ((gran ^ (row & 7)) * 8));
}

// one half-tile stage: 128 rows x 64 cols bf16, 2 issues x (8 waves x 8 rows).
// LDS dest linear; st-swizzle applied by permuting the GLOBAL source granule.
#define STAGE(LDSbuf, SRC, ROW0, K0)                                          \
    {                                                                         \
        _Pragma("unroll")                                                     \
        for (int j = 0; j < 2; ++j) {                                         \
            const __hip_bfloat16* g = (SRC) +                                 \
                (size_t)((ROW0) + j * 64 + wave * 8 + srow) * IN_F + (K0) + sgc; \
            __builtin_amdgcn_global_load_lds(                                 \
                (const __attribute__((address_space(1))) void*)g,             \
                (__attribute__((address_space(3))) void*)((LDSbuf) + (j * 64 + wave * 8) * 64), \
                16, 0, 0);                                                    \
        }                                                                     \
    }

#define RD_A(dst, BUF, HALF, KG)                                              \
    _Pragma("unroll") for (int f = 0; f < 4; ++f)                             \
        dst[f] = ldfrag(BUF, HALF, wm * 64 + f * 16 + fr, (KG) * 4 + fc);

#define RD_B(dst, BUF, KG)                                                    \
    _Pragma("unroll") for (int g2 = 0; g2 < 4; ++g2)                          \
        dst[g2] = ldfrag(BUF, bhalf, brow0 + g2 * 16 + fr, (KG) * 4 + fc);

// barrier; counted lgkm drain (keeps the just-issued next-phase reads in
// flight); sched_barrier pins MFMA after the wait (rule #18); MFMA cluster.
#define PHASE_TAIL(LGK, FA, FB, AIDX)                                         \
    __builtin_amdgcn_s_barrier();                                             \
    asm volatile("s_waitcnt lgkmcnt(" #LGK ")" ::: "memory");                 \
    __builtin_amdgcn_sched_barrier(0);                                        \
    __builtin_amdgcn_s_setprio(1);                                            \
    _Pragma("unroll") for (int f = 0; f < 4; ++f)                             \
    _Pragma("unroll") for (int g2 = 0; g2 < 4; ++g2)                          \
        acc[(AIDX) + f][g2] = __builtin_amdgcn_mfma_f32_16x16x32_bf16(        \
            FA[f], FB[g2], acc[(AIDX) + f][g2], 0, 0, 0);                     \
    __builtin_amdgcn_s_setprio(0);                                            \
    __builtin_amdgcn_s_barrier();

__global__ __launch_bounds__(512, 2) void qlora_gemm_kernel(
    const __hip_bfloat16* __restrict__ xb,   // [M_TOK][IN_F]
    const __hip_bfloat16* __restrict__ Wq,   // [OUT_F][IN_F]  (B^T layout)
    const float* __restrict__ bias,          // [OUT_F]
    float* __restrict__ out) {               // [M_TOK][OUT_F]
    __shared__ __hip_bfloat16 As[2][16384];  // [dbuf][half(2) x 128 x 64] = 64 KB
    __shared__ __hip_bfloat16 Bs[2][16384];  // 64 KB

    const int tid  = threadIdx.x;
    const int wave = tid >> 6;
    const int lane = tid & 63;
    const int wm = wave >> 2;                // 0..1  (M half of wave grid)
    const int wn = wave & 3;                 // 0..3  (N quarter: 64 cols each)

    // T1: bijective XCD swizzle (nwg=512, 512%8==0)
    const int wg = ((int)blockIdx.x & 7) * 64 + ((int)blockIdx.x >> 3);
    const int bx = wg & 15;                  // 16 N-tiles
    const int by = wg >> 4;                  // 32 M-tiles
    const int m0 = by * 256;
    const int n0 = bx * 256;

    f32x4 acc[8][4];
#pragma unroll
    for (int i = 0; i < 8; ++i)
#pragma unroll
        for (int j = 0; j < 4; ++j)
            acc[i][j] = (f32x4){0.f, 0.f, 0.f, 0.f};

    // staging lane geometry: LDS slot p of row r holds global granule (p^(r&7))
    const int srow = lane >> 3;
    const int sgc  = ((lane & 7) ^ srow) * 8;

    // fragment read geometry (16x16x32): row = lane&15, k-granule = lane>>4
    const int fr = lane & 15;
    const int fc = lane >> 4;

    // wave's B slice: contiguous 64 cols = n0 + wn*64; in LDS halves of 128:
    const int bhalf = wn >> 1;
    const int brow0 = (wn & 1) * 64;

    const short* A0p = (const short*)As[0];
    const short* A1p = (const short*)As[1];
    const short* B0p = (const short*)Bs[0];
    const short* B1p = (const short*)Bs[1];

    short8 fa0[4], fa1[4];
    short8 fb0[4], fb1[4];

    // prologue (mimics steady state entering p0(0)):
    //   tile0 all 4 regions (8 loads); then tile1 A0,B0 (4, = p2(-1)) and
    //   tile1 B1 (2, = p3(-1)); vmcnt(6) -> tile0 landed, 6 tile1 loads fly;
    //   then the p0(0) operand reads (= p3(-1)'s read-issues, 8 outstanding).
    STAGE(As[0],        xb, m0,       0);    // t0 A h0
    STAGE(As[0] + 8192, xb, m0 + 128, 0);    // t0 A h1
    STAGE(Bs[0],        Wq, n0,       0);    // t0 B h0
    STAGE(Bs[0] + 8192, Wq, n0 + 128, 0);    // t0 B h1
    STAGE(As[1],        xb, m0,       BK);   // t1 A h0
    STAGE(Bs[1],        Wq, n0,       BK);   // t1 B h0
    STAGE(Bs[1] + 8192, Wq, n0 + 128, BK);   // t1 B h1
    asm volatile("s_waitcnt vmcnt(6)" ::: "memory");
    __builtin_amdgcn_s_barrier();
    RD_A(fa0, A0p, 0, 0);                    // operands for p0(0)
    RD_B(fb0, B0p, 0);

    for (int it = 0; it < NT / 2; ++it) {
        const int t = it * 2;
        const int k_t1 = (t + 1) * BK;               // always in-bounds
        const int k_t2 = ((t + 2) & (NT - 1)) * BK;  // wraps: garbage tail
        const int k_t3 = ((t + 3) & (NT - 1)) * BK;  //  prefetch, in-bounds

        // ---- tile t (buf0 = X, buf1 = Y)
        RD_A(fa1, A0p, 0, 1); RD_B(fb1, B0p, 1);
        STAGE(As[1] + 8192, xb, m0 + 128, k_t1);         // Y.A1 (t+1)
        PHASE_TAIL(8, fa0, fb0, 0)
        RD_A(fa0, A0p, 1, 0);
        PHASE_TAIL(4, fa1, fb1, 0)
        RD_A(fa1, A0p, 1, 1);
        STAGE(As[0], xb, m0, k_t2);                      // X.A0 (t+2)
        STAGE(Bs[0], Wq, n0, k_t2);                      // X.B0 (t+2)
        PHASE_TAIL(4, fa0, fb0, 4)
        asm volatile("s_waitcnt vmcnt(4)" ::: "memory"); // t+1 data all landed
        RD_A(fa0, A1p, 0, 0); RD_B(fb0, B1p, 0);         // operands for p0(t+1)
        STAGE(Bs[0] + 8192, Wq, n0 + 128, k_t2);         // X.B1 (t+2)
        PHASE_TAIL(8, fa1, fb1, 4)

        // ---- tile t+1 (buf1 = X, buf0 = Y)
        RD_A(fa1, A1p, 0, 1); RD_B(fb1, B1p, 1);
        STAGE(As[0] + 8192, xb, m0 + 128, k_t2);         // Y.A1 (t+2)
        PHASE_TAIL(8, fa0, fb0, 0)
        RD_A(fa0, A1p, 1, 0);
        PHASE_TAIL(4, fa1, fb1, 0)
        RD_A(fa1, A1p, 1, 1);
        STAGE(As[1], xb, m0, k_t3);                      // X.A0 (t+3)
        STAGE(Bs[1], Wq, n0, k_t3);                      // X.B0 (t+3)
        PHASE_TAIL(4, fa0, fb0, 4)
        asm volatile("s_waitcnt vmcnt(4)" ::: "memory"); // t+2 data all landed
        RD_A(fa0, A0p, 0, 0); RD_B(fb0, B0p, 0);         // operands for p0(t+2)
        STAGE(Bs[1] + 8192, Wq, n0 + 128, k_t3);         // X.B1 (t+3)
        PHASE_TAIL(8, fa1, fb1, 4)
    }

    // drain leftover (garbage) prefetches before LDS deallocation at endpgm
    asm volatile("s_waitcnt vmcnt(0)" ::: "memory");

    // ---- epilogue: bias + store
    // C/D 16x16: col = lane&15, row = (lane>>4)*4 + reg  (m89-verified)
    const int cc  = lane & 15;
    const int rr4 = (lane >> 4) * 4;
    float bv[4];
#pragma unroll
    for (int g2 = 0; g2 < 4; ++g2)
        bv[g2] = bias[n0 + wn * 64 + g2 * 16 + cc];

#pragma unroll
    for (int mh = 0; mh < 2; ++mh)
#pragma unroll
        for (int f = 0; f < 4; ++f) {
            const int m = m0 + mh * 128 + wm * 64 + f * 16 + rr4;
#pragma unroll
            for (int g2 = 0; g2 < 4; ++g2) {
                const int n = n0 + wn * 64 + g2 * 16 + cc;
                float* op = out + (size_t)m * OUT_F + n;
                const f32x4 a = acc[mh * 4 + f][g2];
#pragma unroll
                for (int r = 0; r < 4; ++r)
                    op[(size_t)r * OUT_F] = a[r] + bv[g2];
            }
        }
}

// ---------------------------------------------------------------------------
extern "C" void kernel_launch(void* const* d_in, const int* in_sizes, int n_in,
                              void* d_out, int out_size, void* d_ws, size_t ws_size,
                              hipStream_t stream) {
    const float* x      = (const float*)d_in[0];   // [8,1024,4096] fp32
    const int*   qw     = (const int*)  d_in[1];   // [4096,4096] int32 codes
    const float* scales = (const float*)d_in[2];   // [4096,64] fp32
    const float* bias   = (const float*)d_in[3];   // [4096] fp32
    const float* lA     = (const float*)d_in[4];   // [4096,16] fp32
    const float* lB     = (const float*)d_in[5];   // [16,4096] fp32
    float* out = (float*)d_out;                    // [8,1024,4096] fp32

    // workspace layout (needs 96 MB)
    char* ws = (char*)d_ws;
    __hip_bfloat16* Wq = (__hip_bfloat16*)ws;                              // 32 MB
    __hip_bfloat16* xb = (__hip_bfloat16*)(ws + (size_t)32 * 1024 * 1024); // 64 MB

    // 1a) streaming x convert
    conv_kernel<<<CONV_BLOCKS, 256, 0, stream>>>(x, xb);
    // 1b) dequant + LoRA fold
    deq_kernel<<<DEQ_BLOCKS, 256, 0, stream>>>(qw, scales, lA, lB, Wq);
    // 2) main GEMM (256x256 tiles, pipelined 8-phase) + bias epilogue
    qlora_gemm_kernel<<<dim3(512), dim3(512), 0, stream>>>(xb, Wq, bias, out);
}

// Round 5
// 581.970 us; speedup vs baseline: 1.0455x; 1.0455x over previous
//
#include <hip/hip_runtime.h>
#include <hip/hip_bf16.h>

#define IN_F 4096
#define OUT_F 4096
#define M_TOK 8192
#define RANK 16

typedef __attribute__((ext_vector_type(4))) float f32x4;
typedef __attribute__((ext_vector_type(8))) short short8;

struct alignas(16) bf16x8_s { __hip_bfloat16 v[8]; };

// ---------------------------------------------------------------------------
// Kernel 1a: streaming convert x fp32 -> bf16. UNCHANGED (attribution round:
// the GEMM split should finally surface this kernel's counters in top-5).
// ---------------------------------------------------------------------------
#define CONV_BLOCKS 2048
#define CONV_ITERS (M_TOK * IN_F / (8 * 256 * CONV_BLOCKS))   // 8

__global__ __launch_bounds__(256) void conv_kernel(
    const float* __restrict__ x,
    __hip_bfloat16* __restrict__ xb) {
    size_t idx = (size_t)blockIdx.x * 256 + threadIdx.x;
    const size_t stride = (size_t)CONV_BLOCKS * 256;
#pragma unroll
    for (int it = 0; it < CONV_ITERS; ++it, idx += stride) {
        const size_t base = idx * 8;
        float4 v0 = *(const float4*)(x + base);
        float4 v1 = *(const float4*)(x + base + 4);
        bf16x8_s r;
        r.v[0] = __float2bfloat16(v0.x);
        r.v[1] = __float2bfloat16(v0.y);
        r.v[2] = __float2bfloat16(v0.z);
        r.v[3] = __float2bfloat16(v0.w);
        r.v[4] = __float2bfloat16(v1.x);
        r.v[5] = __float2bfloat16(v1.y);
        r.v[6] = __float2bfloat16(v1.z);
        r.v[7] = __float2bfloat16(v1.w);
        *(bf16x8_s*)(xb + base) = r;
    }
}

// ---------------------------------------------------------------------------
// Kernel 1b: dequant int4 codes -> bf16 with rank-16 LoRA folded in. UNCHANGED.
//   W[o][i] = bf16( scales[o][i/64]*(q-8) + 2*sum_r A[i][r]*B[r][o] )
// ---------------------------------------------------------------------------
#define DEQ_BLOCKS 2048

__global__ __launch_bounds__(256) void deq_kernel(
    const int* __restrict__ q,
    const float* __restrict__ scales,
    const float* __restrict__ lA,   // [IN_F][RANK]
    const float* __restrict__ lB,   // [RANK][OUT_F]
    __hip_bfloat16* __restrict__ W) {
    const int tid = threadIdx.x;
    const int bid = blockIdx.x;                  // 0..2047
    const int o0 = (bid >> 1) * 4;               // block-uniform
    const int i0 = (bid & 1) * 2048 + tid * 8;

    float bw[16][4];
#pragma unroll
    for (int r = 0; r < 16; ++r)
#pragma unroll
        for (int oi = 0; oi < 4; ++oi)
            bw[r][oi] = 2.0f * lB[(size_t)r * OUT_F + o0 + oi];

    float fold[4][8];
#pragma unroll
    for (int e = 0; e < 8; ++e) {
        const float* ar = lA + (size_t)(i0 + e) * RANK;
        float4 a0 = *(const float4*)(ar + 0);
        float4 a1 = *(const float4*)(ar + 4);
        float4 a2 = *(const float4*)(ar + 8);
        float4 a3 = *(const float4*)(ar + 12);
#pragma unroll
        for (int oi = 0; oi < 4; ++oi) {
            float f = a0.x * bw[0][oi] + a0.y * bw[1][oi]
                    + a0.z * bw[2][oi] + a0.w * bw[3][oi]
                    + a1.x * bw[4][oi] + a1.y * bw[5][oi]
                    + a1.z * bw[6][oi] + a1.w * bw[7][oi]
                    + a2.x * bw[8][oi] + a2.y * bw[9][oi]
                    + a2.z * bw[10][oi] + a2.w * bw[11][oi]
                    + a3.x * bw[12][oi] + a3.y * bw[13][oi]
                    + a3.z * bw[14][oi] + a3.w * bw[15][oi];
            fold[oi][e] = f;
        }
    }

#pragma unroll
    for (int oi = 0; oi < 4; ++oi) {
        const int o = o0 + oi;
        const float s = scales[o * 64 + (i0 >> 6)];
        const int4* qp = (const int4*)(q + (size_t)o * IN_F + i0);
        int4 q0 = qp[0];
        int4 q1 = qp[1];
        bf16x8_s r;
        r.v[0] = __float2bfloat16(s * (float)(q0.x - 8) + fold[oi][0]);
        r.v[1] = __float2bfloat16(s * (float)(q0.y - 8) + fold[oi][1]);
        r.v[2] = __float2bfloat16(s * (float)(q0.z - 8) + fold[oi][2]);
        r.v[3] = __float2bfloat16(s * (float)(q0.w - 8) + fold[oi][3]);
        r.v[4] = __float2bfloat16(s * (float)(q1.x - 8) + fold[oi][4]);
        r.v[5] = __float2bfloat16(s * (float)(q1.y - 8) + fold[oi][5]);
        r.v[6] = __float2bfloat16(s * (float)(q1.z - 8) + fold[oi][6]);
        r.v[7] = __float2bfloat16(s * (float)(q1.w - 8) + fold[oi][7]);
        *(bf16x8_s*)(W + (size_t)o * IN_F + i0) = r;
    }
}

// ---------------------------------------------------------------------------
// Kernel 2: 256x256 GEMM, R5: COMPILER-SCHEDULED phase bodies.
// R3/R4's sched_barrier(0)+asm-lgkm walls serialized the LDS pipe against the
// MFMA pipe (read-window ~400cy + MFMA 621cy strictly alternating -> 5590
// cyc/K-tile). m97 evidence: the compiler interleaves ds_read<->MFMA with its
// own counted lgkmcnt when left alone. So each phase is now ONE s_barrier +
// a freely-scheduled body {4-8 ldfrag loads, 16 MFMAs, stage issues}; no
// sched_barrier, no asm lgkm, no setprio. Counted vmcnt(4) asm kept (compiler
// can't see global_load_lds -> ds_read deps); it is also the fence that stops
// next-tile reads hoisting across the barrier.
//
// Single-barrier-per-phase safety: each phase's reads are consumed by its own
// MFMAs (hardware lgkm interlock) before the wave reaches the next barrier,
// so a stage issued after that barrier can never race them. Stage map
// (4 phases/K-tile, p0..p3; X=buf[t&1], Y=other):
//   p0: rd A(h0,k0)+B(k0); stage Y.A1(t+1)   [Y.A1 last read p3(t-1)]
//   p1: rd A(h1,k0);        stage Y.B1(t+1)   [Y.B1 last read p2(t-1)]
//   p2: rd A(h0,k1)+B(k1);  (no stage)
//   p3: rd A(h1,k1);        stage X.A0+X.B0(t+2) [last read p2(t)]; vmcnt(4)
// vmcnt(4) at p3 end: outstanding = p0:2 + p1:2 + p3:4 = 8 -> drains t+1's
// A1,B1 (A0,B0 of t+1 drained by t-1's vmcnt), keeps p3's 4 (t+2) in flight.
// Never vmcnt(0)/lgkmcnt(0) in the loop.
//
// Launched TWICE (M=4096 halves, grid 256 = 1 block/CU) so each dispatch is
// ~100us -> prep kernels can surface in rocprof top-5 for attribution.
// ---------------------------------------------------------------------------
#define BK 64
#define NT (IN_F / BK)   // 64 K-tiles

__device__ __forceinline__ short8 ldfrag(const short* p, int half, int row, int gran) {
    // swizzled read: LDS granule slot (gran ^ (row&7)) holds global granule gran
    return *(const short8*)(p + half * 8192 + row * 64 + ((gran ^ (row & 7)) * 8));
}

// one half-tile stage: 128 rows x 64 cols bf16, 2 issues x (8 waves x 8 rows).
// LDS dest linear; st-swizzle applied by permuting the GLOBAL source granule.
#define STAGE(LDSbuf, SRC, ROW0, K0)                                          \
    {                                                                         \
        _Pragma("unroll")                                                     \
        for (int j = 0; j < 2; ++j) {                                         \
            const __hip_bfloat16* g = (SRC) +                                 \
                (size_t)((ROW0) + j * 64 + wave * 8 + srow) * IN_F + (K0) + sgc; \
            __builtin_amdgcn_global_load_lds(                                 \
                (const __attribute__((address_space(1))) void*)g,             \
                (__attribute__((address_space(3))) void*)((LDSbuf) + (j * 64 + wave * 8) * 64), \
                16, 0, 0);                                                    \
        }                                                                     \
    }

#define RD_A(BUF, HALF, KG)                                                   \
    _Pragma("unroll") for (int f = 0; f < 4; ++f)                             \
        fa[f] = ldfrag(BUF, HALF, wm * 64 + f * 16 + fr, (KG) * 4 + fc);

#define RD_B(BUF, KG)                                                         \
    _Pragma("unroll") for (int g2 = 0; g2 < 4; ++g2)                          \
        fb[g2] = ldfrag(BUF, bhalf, brow0 + g2 * 16 + fr, (KG) * 4 + fc);

#define MFMA16(MH)                                                            \
    _Pragma("unroll") for (int f = 0; f < 4; ++f)                             \
    _Pragma("unroll") for (int g2 = 0; g2 < 4; ++g2)                          \
        acc[(MH) * 4 + f][g2] = __builtin_amdgcn_mfma_f32_16x16x32_bf16(      \
            fa[f], fb[g2], acc[(MH) * 4 + f][g2], 0, 0, 0);

#define BAR __builtin_amdgcn_s_barrier();

__global__ __launch_bounds__(512, 2) void qlora_gemm_kernel(
    const __hip_bfloat16* __restrict__ xb,   // [4096][IN_F] half-panel
    const __hip_bfloat16* __restrict__ Wq,   // [OUT_F][IN_F]  (B^T layout)
    const float* __restrict__ bias,          // [OUT_F]
    float* __restrict__ out) {               // [4096][OUT_F] half-panel
    __shared__ __hip_bfloat16 As[2][16384];  // [dbuf][half(2) x 128 x 64] = 64 KB
    __shared__ __hip_bfloat16 Bs[2][16384];  // 64 KB

    const int tid  = threadIdx.x;
    const int wave = tid >> 6;
    const int lane = tid & 63;
    const int wm = wave >> 2;                // 0..1  (M half of wave grid)
    const int wn = wave & 3;                 // 0..3  (N quarter: 64 cols each)

    // T1: bijective XCD swizzle (nwg=256, 256%8==0)
    const int wg = ((int)blockIdx.x & 7) * 32 + ((int)blockIdx.x >> 3);
    const int bx = wg & 15;                  // 16 N-tiles
    const int by = wg >> 4;                  // 16 M-tiles (half panel)
    const int m0 = by * 256;
    const int n0 = bx * 256;

    f32x4 acc[8][4];
#pragma unroll
    for (int i = 0; i < 8; ++i)
#pragma unroll
        for (int j = 0; j < 4; ++j)
            acc[i][j] = (f32x4){0.f, 0.f, 0.f, 0.f};

    // staging lane geometry: LDS slot p of row r holds global granule (p^(r&7))
    const int srow = lane >> 3;
    const int sgc  = ((lane & 7) ^ srow) * 8;

    // fragment read geometry (16x16x32): row = lane&15, k-granule = lane>>4
    const int fr = lane & 15;
    const int fc = lane >> 4;

    // wave's B slice: contiguous 64 cols = n0 + wn*64; in LDS halves of 128:
    const int bhalf = wn >> 1;
    const int brow0 = (wn & 1) * 64;

    const short* A0p = (const short*)As[0];
    const short* A1p = (const short*)As[1];
    const short* B0p = (const short*)Bs[0];
    const short* B1p = (const short*)Bs[1];

    short8 fa[4];
    short8 fb[4];

    // prologue: tile0 (buf0) all 4 regions (8 loads); tile1 A0,B0 (4 loads,
    // = steady-state p3(-1)); vmcnt(4) drains tile0, keeps tile1's 4 in flight
    STAGE(As[0],        xb, m0,       0);    // t0 A h0
    STAGE(As[0] + 8192, xb, m0 + 128, 0);    // t0 A h1
    STAGE(Bs[0],        Wq, n0,       0);    // t0 B h0
    STAGE(Bs[0] + 8192, Wq, n0 + 128, 0);    // t0 B h1
    STAGE(As[1],        xb, m0,       BK);   // t1 A h0
    STAGE(Bs[1],        Wq, n0,       BK);   // t1 B h0
    asm volatile("s_waitcnt vmcnt(4)" ::: "memory");

    for (int it = 0; it < NT / 2; ++it) {
        const int t = it * 2;
        const int k_t1 = (t + 1) * BK;               // always in-bounds
        const int k_t2 = ((t + 2) & (NT - 1)) * BK;  // wraps: garbage tail
        const int k_t3 = ((t + 3) & (NT - 1)) * BK;  //  prefetch, in-bounds

        // ---- tile t (buf0 = X, buf1 = Y)
        BAR RD_A(A0p, 0, 0) RD_B(B0p, 0)
            STAGE(As[1] + 8192, xb, m0 + 128, k_t1)  // Y.A1 (t+1)
            MFMA16(0)
        BAR RD_A(A0p, 1, 0)
            STAGE(Bs[1] + 8192, Wq, n0 + 128, k_t1)  // Y.B1 (t+1)
            MFMA16(1)
        BAR RD_A(A0p, 0, 1) RD_B(B0p, 1)
            MFMA16(0)
        BAR RD_A(A0p, 1, 1)
            STAGE(As[0], xb, m0, k_t2)               // X.A0 (t+2)
            STAGE(Bs[0], Wq, n0, k_t2)               // X.B0 (t+2)
            MFMA16(1)
        asm volatile("s_waitcnt vmcnt(4)" ::: "memory");  // t+1 fully landed

        // ---- tile t+1 (buf1 = X, buf0 = Y)
        BAR RD_A(A1p, 0, 0) RD_B(B1p, 0)
            STAGE(As[0] + 8192, xb, m0 + 128, k_t2)  // Y.A1 (t+2)
            MFMA16(0)
        BAR RD_A(A1p, 1, 0)
            STAGE(Bs[0] + 8192, Wq, n0 + 128, k_t2)  // Y.B1 (t+2)
            MFMA16(1)
        BAR RD_A(A1p, 0, 1) RD_B(B1p, 1)
            MFMA16(0)
        BAR RD_A(A1p, 1, 1)
            STAGE(As[1], xb, m0, k_t3)               // X.A0 (t+3)
            STAGE(Bs[1], Wq, n0, k_t3)               // X.B0 (t+3)
            MFMA16(1)
        asm volatile("s_waitcnt vmcnt(4)" ::: "memory");  // t+2 fully landed
    }

    // drain leftover (garbage) prefetches before LDS deallocation at endpgm
    asm volatile("s_waitcnt vmcnt(0)" ::: "memory");

    // ---- epilogue: bias + store
    // C/D 16x16: col = lane&15, row = (lane>>4)*4 + reg  (m89-verified)
    const int cc  = lane & 15;
    const int rr4 = (lane >> 4) * 4;
    float bv[4];
#pragma unroll
    for (int g2 = 0; g2 < 4; ++g2)
        bv[g2] = bias[n0 + wn * 64 + g2 * 16 + cc];

#pragma unroll
    for (int mh = 0; mh < 2; ++mh)
#pragma unroll
        for (int f = 0; f < 4; ++f) {
            const int m = m0 + mh * 128 + wm * 64 + f * 16 + rr4;
#pragma unroll
            for (int g2 = 0; g2 < 4; ++g2) {
                const int n = n0 + wn * 64 + g2 * 16 + cc;
                float* op = out + (size_t)m * OUT_F + n;
                const f32x4 a = acc[mh * 4 + f][g2];
#pragma unroll
                for (int r = 0; r < 4; ++r)
                    op[(size_t)r * OUT_F] = a[r] + bv[g2];
            }
        }
}

// ---------------------------------------------------------------------------
extern "C" void kernel_launch(void* const* d_in, const int* in_sizes, int n_in,
                              void* d_out, int out_size, void* d_ws, size_t ws_size,
                              hipStream_t stream) {
    const float* x      = (const float*)d_in[0];   // [8,1024,4096] fp32
    const int*   qw     = (const int*)  d_in[1];   // [4096,4096] int32 codes
    const float* scales = (const float*)d_in[2];   // [4096,64] fp32
    const float* bias   = (const float*)d_in[3];   // [4096] fp32
    const float* lA     = (const float*)d_in[4];   // [4096,16] fp32
    const float* lB     = (const float*)d_in[5];   // [16,4096] fp32
    float* out = (float*)d_out;                    // [8,1024,4096] fp32

    // workspace layout (needs 96 MB)
    char* ws = (char*)d_ws;
    __hip_bfloat16* Wq = (__hip_bfloat16*)ws;                              // 32 MB
    __hip_bfloat16* xb = (__hip_bfloat16*)(ws + (size_t)32 * 1024 * 1024); // 64 MB

    // 1a) streaming x convert
    conv_kernel<<<CONV_BLOCKS, 256, 0, stream>>>(x, xb);
    // 1b) dequant + LoRA fold
    deq_kernel<<<DEQ_BLOCKS, 256, 0, stream>>>(qw, scales, lA, lB, Wq);
    // 2) main GEMM in two M=4096 halves (grid 256 = 1 block/CU each)
    const size_t half = (size_t)4096 * IN_F;        // bf16 elements
    const size_t ohalf = (size_t)4096 * OUT_F;      // fp32 elements
    qlora_gemm_kernel<<<dim3(256), dim3(512), 0, stream>>>(xb, Wq, bias, out);
    qlora_gemm_kernel<<<dim3(256), dim3(512), 0, stream>>>(xb + half, Wq, bias, out + ohalf);
}